// Round 1
// baseline (410.993 us; speedup 1.0000x reference)
//
#include <hip/hip_runtime.h>
#include <hip/hip_bf16.h>

// RelativeAttention: out = softmax((QK^T + Sh + Sw)/8) V,  Q/K/V = feature @ W^T + b
// B=2, N=4096, D=512, DK=64.  Memory-bound on streaming Sh+Sw (268 MB).

typedef short bf16x8 __attribute__((ext_vector_type(8)));
typedef short bf16x4 __attribute__((ext_vector_type(4)));
typedef float f32x4  __attribute__((ext_vector_type(4)));

#if __has_builtin(__builtin_amdgcn_exp2f)
#define EXP2F(x) __builtin_amdgcn_exp2f(x)
#else
#define EXP2F(x) exp2f(x)
#endif

__device__ __forceinline__ f32x4 mfma16(bf16x8 a, bf16x8 b, f32x4 c) {
  return __builtin_amdgcn_mfma_f32_16x16x32_bf16(a, b, c, 0, 0, 0);
}
__device__ __forceinline__ short f2b(float x) {
  __hip_bfloat16 h = __float2bfloat16(x);
  return __builtin_bit_cast(short, h);
}
__device__ __forceinline__ float b2f(short s) {
  return __bfloat162float(__builtin_bit_cast(__hip_bfloat16, s));
}
__device__ __forceinline__ void split_hl(float x, short& h, short& l) {
  __hip_bfloat16 bh = __float2bfloat16(x);
  h = __builtin_bit_cast(short, bh);
  l = f2b(x - __bfloat162float(bh));
}

// ---------------- kernel 1: weight fp32 -> bf16 hi/lo ----------------
// 3 matrices of 64x512 = 32768 elems each. grid 96 x 256, 4 elems/thread.
__global__ void wcvt_kernel(const float* __restrict__ wq, const float* __restrict__ wk,
                            const float* __restrict__ wv,
                            short* __restrict__ wh, short* __restrict__ wl) {
  int idx = (blockIdx.x * 256 + threadIdx.x) * 4;
  int p = idx >> 15;
  int off = idx & 32767;
  const float* src = (p == 0) ? wq : (p == 1) ? wk : wv;
  f32x4 v = *(const f32x4*)(src + off);
  bf16x4 h, l;
#pragma unroll
  for (int j = 0; j < 4; ++j) { short hh, ll; split_hl(v[j], hh, ll); h[j] = hh; l[j] = ll; }
  *(bf16x4*)(wh + p * 32768 + off) = h;
  *(bf16x4*)(wl + p * 32768 + off) = l;
}

// ---------------- kernel 2: projections (fp32-accurate via hi/lo MFMA) ----------------
// 1 wave/block, 16 rows/wave, 512 blocks.  Outputs Qh/Ql/Kh/Kl [row8192][64] bf16,
// Vt [b][dv=64][n=4096] bf16 (transposed so PV B-frag loads are contiguous).
__global__ __launch_bounds__(64) void proj_kernel(
    const float* __restrict__ feat, const short* __restrict__ wh, const short* __restrict__ wl,
    const float* __restrict__ bq, const float* __restrict__ bk, const float* __restrict__ bv,
    short* __restrict__ Qh, short* __restrict__ Ql,
    short* __restrict__ Kh, short* __restrict__ Kl, short* __restrict__ Vt) {
  int lane = threadIdx.x & 63;
  int lq = lane & 15, quad = lane >> 4;
  int rbase = blockIdx.x * 16;
  f32x4 acc[3][4];
#pragma unroll
  for (int p = 0; p < 3; ++p)
#pragma unroll
    for (int t = 0; t < 4; ++t) acc[p][t] = (f32x4){0.f, 0.f, 0.f, 0.f};

  const float* frow = feat + (size_t)(rbase + lq) * 512 + quad * 8;
  for (int ks = 0; ks < 16; ++ks) {
    f32x4 f0 = *(const f32x4*)(frow + ks * 32);
    f32x4 f1 = *(const f32x4*)(frow + ks * 32 + 4);
    bf16x8 fh, fl;
#pragma unroll
    for (int j = 0; j < 4; ++j) {
      short hh, ll;
      split_hl(f0[j], hh, ll); fh[j] = hh; fl[j] = ll;
      split_hl(f1[j], hh, ll); fh[j + 4] = hh; fl[j + 4] = ll;
    }
#pragma unroll
    for (int p = 0; p < 3; ++p)
#pragma unroll
      for (int t = 0; t < 4; ++t) {
        const int wo = (p * 64 + t * 16 + lq) * 512 + ks * 32 + quad * 8;
        bf16x8 wfh = *(const bf16x8*)(wh + wo);
        bf16x8 wfl = *(const bf16x8*)(wl + wo);
        acc[p][t] = mfma16(fh, wfh, acc[p][t]);
        acc[p][t] = mfma16(fl, wfh, acc[p][t]);
        acc[p][t] = mfma16(fh, wfl, acc[p][t]);
      }
  }
  int b = rbase >> 12;
  int rloc = rbase & 4095;
#pragma unroll
  for (int t = 0; t < 4; ++t) {
    int dk = t * 16 + lq;
    float bqv = bq[dk], bkv = bk[dk], bvv = bv[dk];
    bf16x4 vpack;
#pragma unroll
    for (int r = 0; r < 4; ++r) {
      int row = rbase + 4 * quad + r;
      short h, l;
      split_hl(acc[0][t][r] + bqv, h, l);
      Qh[row * 64 + dk] = h; Ql[row * 64 + dk] = l;
      split_hl(acc[1][t][r] + bkv, h, l);
      Kh[row * 64 + dk] = h; Kl[row * 64 + dk] = l;
      vpack[r] = f2b(acc[2][t][r] + bvv);
    }
    *(bf16x4*)(Vt + (size_t)(b * 64 + dk) * 4096 + rloc + 4 * quad) = vpack;
  }
}

// ---------------- kernel 3: fused biased attention, split-K ----------------
// grid = B(2) * qtiles(64) * splits(8) = 1024 blocks, 256 threads (4 waves).
// Wave w: q rows [qt*64+w*16, +16).  Key chunk = 512 keys, 16 iters of 32.
// No running max needed: |log2-domain scores| < ~20, exp2 cannot overflow fp32.
__global__ __launch_bounds__(256, 4) void attn_kernel(
    const float* __restrict__ Sh, const float* __restrict__ Sw,
    const short* __restrict__ Qh, const short* __restrict__ Ql,
    const short* __restrict__ Kh, const short* __restrict__ Kl,
    const short* __restrict__ Vt,
    float* __restrict__ Opart, float* __restrict__ lpart) {
  __shared__ short Plds[4][16][40];  // per-wave P buffer, stride 40 -> 16B-aligned b128 reads
  const int bid = blockIdx.x;
  const int sp = bid & 7, qt = (bid >> 3) & 63, b = bid >> 9;
  const int tid = threadIdx.x;
  const int wave = tid >> 6, lane = tid & 63, lq = lane & 15, quad = lane >> 4;
  const int qbase = qt * 64 + wave * 16;

  bf16x8 qfh[2], qfl[2];
  {
    const int qidx = (b * 4096 + qbase + lq) * 64 + quad * 8;
    qfh[0] = *(const bf16x8*)(Qh + qidx);
    qfh[1] = *(const bf16x8*)(Qh + qidx + 32);
    qfl[0] = *(const bf16x8*)(Ql + qidx);
    qfl[1] = *(const bf16x8*)(Ql + qidx + 32);
  }
  f32x4 accO[4];
#pragma unroll
  for (int u = 0; u < 4; ++u) accO[u] = (f32x4){0.f, 0.f, 0.f, 0.f};
  float lsum[4] = {0.f, 0.f, 0.f, 0.f};
  const float Cs = 0.18033688011112042f;  // log2(e)/8
  const size_t biasRow = (size_t)(b * 4096 + qbase + 4 * quad) * 4096;
  short* pw = &Plds[wave][0][0];

  for (int it = 0; it < 16; ++it) {
    const int kb = sp * 512 + it * 32;
    f32x4 accS[2];
    accS[0] = (f32x4){0.f, 0.f, 0.f, 0.f};
    accS[1] = (f32x4){0.f, 0.f, 0.f, 0.f};
#pragma unroll
    for (int t = 0; t < 2; ++t) {
      const int kidx = (b * 4096 + kb + t * 16 + lq) * 64 + quad * 8;
      bf16x8 kh0 = *(const bf16x8*)(Kh + kidx);
      bf16x8 kh1 = *(const bf16x8*)(Kh + kidx + 32);
      bf16x8 kl0 = *(const bf16x8*)(Kl + kidx);
      bf16x8 kl1 = *(const bf16x8*)(Kl + kidx + 32);
      // hi/lo split QK^T: Qh*Kh + Ql*Kh + Qh*Kl  (near-fp32 logits)
      accS[t] = mfma16(qfh[0], kh0, accS[t]);
      accS[t] = mfma16(qfh[1], kh1, accS[t]);
      accS[t] = mfma16(qfl[0], kh0, accS[t]);
      accS[t] = mfma16(qfl[1], kh1, accS[t]);
      accS[t] = mfma16(qfh[0], kl0, accS[t]);
      accS[t] = mfma16(qfh[1], kl1, accS[t]);
    }
    // bias add + exp2 (non-temporal: Sh/Sw are stream-once, keep K/V in L2)
#pragma unroll
    for (int t = 0; t < 2; ++t) {
#pragma unroll
      for (int r = 0; r < 4; ++r) {
        const size_t bi = biasRow + (size_t)r * 4096 + (kb + t * 16 + lq);
        float s = accS[t][r] + __builtin_nontemporal_load(Sh + bi)
                            + __builtin_nontemporal_load(Sw + bi);
        float p = EXP2F(s * Cs);
        lsum[r] += p;
        pw[(4 * quad + r) * 40 + t * 16 + lq] = f2b(p);
      }
    }
    // wave-private LDS transpose: C-layout (q=4*quad+r, key=lane&15)
    //   -> A-layout (q=lane&15, key=quad*8+j).  Same wave: no barrier needed.
    bf16x8 pa = *(const bf16x8*)(pw + lq * 40 + quad * 8);
#pragma unroll
    for (int u = 0; u < 4; ++u) {
      const bf16x8 vf = *(const bf16x8*)(Vt + (size_t)(b * 64 + u * 16 + lq) * 4096 + kb + quad * 8);
      accO[u] = mfma16(pa, vf, accO[u]);
    }
  }
  // row-sum of P across the 16 key-lanes (once per block, not per iter)
#pragma unroll
  for (int r = 0; r < 4; ++r)
#pragma unroll
    for (int m = 1; m < 16; m <<= 1) lsum[r] += __shfl_xor(lsum[r], m, 64);

  const int orow = sp * 8192 + b * 4096 + qbase + 4 * quad;
#pragma unroll
  for (int r = 0; r < 4; ++r) {
#pragma unroll
    for (int u = 0; u < 4; ++u)
      Opart[(size_t)(orow + r) * 64 + u * 16 + lq] = accO[u][r];
    if (lq == 0) lpart[orow + r] = lsum[r];
  }
}

// ---------------- kernel 4: combine splits ----------------
__global__ void combine_kernel(const float* __restrict__ Opart, const float* __restrict__ lpart,
                               float* __restrict__ out) {
  int g = blockIdx.x * 256 + threadIdx.x;  // 0..524287
  int row = g >> 6;
  float o = 0.f, l = 0.f;
#pragma unroll
  for (int s = 0; s < 8; ++s) {
    o += __builtin_nontemporal_load(Opart + (size_t)s * 524288 + g);
    l += lpart[s * 8192 + row];
  }
  out[g] = o / l;
}

extern "C" void kernel_launch(void* const* d_in, const int* in_sizes, int n_in,
                              void* d_out, int out_size, void* d_ws, size_t ws_size,
                              hipStream_t stream) {
  const float* feature = (const float*)d_in[0];
  const float* Sh = (const float*)d_in[1];
  const float* Sw = (const float*)d_in[2];
  const float* wq = (const float*)d_in[3];
  const float* bq = (const float*)d_in[4];
  const float* wk = (const float*)d_in[5];
  const float* bk = (const float*)d_in[6];
  const float* wv = (const float*)d_in[7];
  const float* bv = (const float*)d_in[8];

  char* ws = (char*)d_ws;
  const size_t MB = 1u << 20;
  short* Qh = (short*)(ws + 0 * MB);            // 1 MB   (8192*64 bf16)
  short* Ql = (short*)(ws + 1 * MB);            // 1 MB
  short* Kh = (short*)(ws + 2 * MB);            // 1 MB
  short* Kl = (short*)(ws + 3 * MB);            // 1 MB
  short* Vt = (short*)(ws + 4 * MB);            // 1 MB   [b][64][4096]
  short* wh = (short*)(ws + 5 * MB);            // 192 KB
  short* wl = (short*)(ws + 5 * MB + 262144);   // 192 KB
  float* lpart = (float*)(ws + 5 * MB + 524288);// 256 KB [8][8192]
  float* Opart = (float*)(ws + 6 * MB);         // 16.78 MB [8][8192][64]

  wcvt_kernel<<<96, 256, 0, stream>>>(wq, wk, wv, wh, wl);
  proj_kernel<<<512, 64, 0, stream>>>(feature, wh, wl, bq, bk, bv, Qh, Ql, Kh, Kl, Vt);
  attn_kernel<<<1024, 256, 0, stream>>>(Sh, Sw, Qh, Ql, Kh, Kl, Vt, Opart, lpart);
  combine_kernel<<<2048, 256, 0, stream>>>(Opart, lpart, (float*)d_out);
}

// Round 2
// 398.546 us; speedup vs baseline: 1.0312x; 1.0312x over previous
//
#include <hip/hip_runtime.h>
#include <hip/hip_bf16.h>

// RelativeAttention: out = softmax((QK^T + Sh + Sw)/8) V,  Q/K/V = feature @ W^T + b
// B=2, N=4096, D=512, DK=64.  Memory-bound on streaming Sh+Sw (268 MB -> ~45 us floor).
// R2: transposed-score layout so bias loads are float4; p-split proj; vector combine.

typedef short bf16x8 __attribute__((ext_vector_type(8)));
typedef short bf16x4 __attribute__((ext_vector_type(4)));
typedef float f32x4  __attribute__((ext_vector_type(4)));

#if __has_builtin(__builtin_amdgcn_exp2f)
#define EXP2F(x) __builtin_amdgcn_exp2f(x)
#else
#define EXP2F(x) exp2f(x)
#endif
#if __has_builtin(__builtin_amdgcn_rcpf)
#define RCPF(x) __builtin_amdgcn_rcpf(x)
#else
#define RCPF(x) (1.0f / (x))
#endif

__device__ __forceinline__ f32x4 mfma16(bf16x8 a, bf16x8 b, f32x4 c) {
  return __builtin_amdgcn_mfma_f32_16x16x32_bf16(a, b, c, 0, 0, 0);
}
__device__ __forceinline__ short f2b(float x) {
  __hip_bfloat16 h = __float2bfloat16(x);
  return __builtin_bit_cast(short, h);
}
__device__ __forceinline__ void split_hl(float x, short& h, short& l) {
  __hip_bfloat16 bh = __float2bfloat16(x);
  h = __builtin_bit_cast(short, bh);
  l = f2b(x - __bfloat162float(bh));
}

// ---------------- kernel 1: weight fp32 -> bf16 hi/lo ----------------
__global__ void wcvt_kernel(const float* __restrict__ wq, const float* __restrict__ wk,
                            const float* __restrict__ wv,
                            short* __restrict__ wh, short* __restrict__ wl) {
  int idx = (blockIdx.x * 256 + threadIdx.x) * 4;
  int p = idx >> 15;
  int off = idx & 32767;
  const float* src = (p == 0) ? wq : (p == 1) ? wk : wv;
  f32x4 v = *(const f32x4*)(src + off);
  bf16x4 h, l;
#pragma unroll
  for (int j = 0; j < 4; ++j) { short hh, ll; split_hl(v[j], hh, ll); h[j] = hh; l[j] = ll; }
  *(bf16x4*)(wh + p * 32768 + off) = h;
  *(bf16x4*)(wl + p * 32768 + off) = l;
}

// ---------------- kernel 2: projections, p-split across waves ----------------
// 1536 waves = 384 blocks x 4 waves.  wave -> (p, 16-row group).
// Q is pre-scaled by log2(e)/8 so attn does exp2(acc + (Sh+Sw)*Cs) directly.
__global__ __launch_bounds__(256) void proj_kernel(
    const float* __restrict__ feat, const short* __restrict__ wh, const short* __restrict__ wl,
    const float* __restrict__ bq, const float* __restrict__ bk, const float* __restrict__ bv,
    short* __restrict__ Qh, short* __restrict__ Ql,
    short* __restrict__ Kh, short* __restrict__ Kl, short* __restrict__ Vt) {
  const int lane = threadIdx.x & 63, wave = threadIdx.x >> 6;
  const int lq = lane & 15, quad = lane >> 4;
  const int wid = blockIdx.x * 4 + wave;   // 0..1535
  const int p = wid >> 9, rg = wid & 511;
  const int rbase = rg * 16;
  const float Cs = 0.18033688011112042f;   // log2(e)/8

  f32x4 acc[4];
#pragma unroll
  for (int t = 0; t < 4; ++t) acc[t] = (f32x4){0.f, 0.f, 0.f, 0.f};

  const float* frow = feat + (size_t)(rbase + lq) * 512 + quad * 8;
  const int wrow = p * 64;
  for (int ks = 0; ks < 16; ++ks) {
    f32x4 f0 = *(const f32x4*)(frow + ks * 32);
    f32x4 f1 = *(const f32x4*)(frow + ks * 32 + 4);
    bf16x8 fh, fl;
#pragma unroll
    for (int j = 0; j < 4; ++j) {
      short hh, ll;
      split_hl(f0[j], hh, ll); fh[j] = hh; fl[j] = ll;
      split_hl(f1[j], hh, ll); fh[j + 4] = hh; fl[j + 4] = ll;
    }
#pragma unroll
    for (int t = 0; t < 4; ++t) {
      const int wo = (wrow + t * 16 + lq) * 512 + ks * 32 + quad * 8;
      bf16x8 wfh = *(const bf16x8*)(wh + wo);
      bf16x8 wfl = *(const bf16x8*)(wl + wo);
      acc[t] = mfma16(fh, wfh, acc[t]);
      acc[t] = mfma16(fl, wfh, acc[t]);
      acc[t] = mfma16(fh, wfl, acc[t]);
    }
  }
  const int b = rbase >> 12, rloc = rbase & 4095;
  if (p == 0) {
#pragma unroll
    for (int t = 0; t < 4; ++t) {
      const int dk = t * 16 + lq;
      const float bb = bq[dk];
#pragma unroll
      for (int r = 0; r < 4; ++r) {
        const int row = rbase + 4 * quad + r;
        short h, l;
        split_hl((acc[t][r] + bb) * Cs, h, l);
        Qh[row * 64 + dk] = h; Ql[row * 64 + dk] = l;
      }
    }
  } else if (p == 1) {
#pragma unroll
    for (int t = 0; t < 4; ++t) {
      const int dk = t * 16 + lq;
      const float bb = bk[dk];
#pragma unroll
      for (int r = 0; r < 4; ++r) {
        const int row = rbase + 4 * quad + r;
        short h, l;
        split_hl(acc[t][r] + bb, h, l);
        Kh[row * 64 + dk] = h; Kl[row * 64 + dk] = l;
      }
    }
  } else {
#pragma unroll
    for (int t = 0; t < 4; ++t) {
      const int dk = t * 16 + lq;
      const float bb = bv[dk];
      bf16x4 vpack;
#pragma unroll
      for (int r = 0; r < 4; ++r) vpack[r] = f2b(acc[t][r] + bb);
      *(bf16x4*)(Vt + (size_t)(b * 64 + dk) * 4096 + rloc + 4 * quad) = vpack;
    }
  }
}

// ---------------- kernel 3: fused biased attention, split-K ----------------
// grid = B(2) * qtiles(64) * splits(8) = 1024 blocks, 256 threads (4 waves).
// Scores computed TRANSPOSED (K as A-operand): D[m=key=4*quad+reg][n=q=lane&15],
// so bias (Sh+Sw)[q][key] is a single aligned float4 per tile per lane.
// No running max (|log2 scores| < ~20, fp32 exp2 cannot overflow); no barriers.
__global__ __launch_bounds__(256, 4) void attn_kernel(
    const float* __restrict__ Sh, const float* __restrict__ Sw,
    const short* __restrict__ Qh, const short* __restrict__ Ql,
    const short* __restrict__ Kh, const short* __restrict__ Kl,
    const short* __restrict__ Vt,
    float* __restrict__ Opart, float* __restrict__ lpart) {
  __shared__ short Plds[4][16][72];  // per-wave P[q16][key64] bf16, stride 72 (144B, 16B-mult)
  const int bid = blockIdx.x;
  const int sp = bid & 7, qt = (bid >> 3) & 63, b = bid >> 9;
  const int tid = threadIdx.x;
  const int wave = tid >> 6, lane = tid & 63, lq = lane & 15, quad = lane >> 4;
  const int qbase = qt * 64 + wave * 16;
  const float Cs = 0.18033688011112042f;  // log2(e)/8 (Q already pre-scaled)

  // Q B-fragments: B[k=dk][n=q] -> lane holds Q[q=lq][dk=quad*8+j]
  const int qidx = (b * 4096 + qbase + lq) * 64 + quad * 8;
  const bf16x8 qfh0 = *(const bf16x8*)(Qh + qidx);
  const bf16x8 qfh1 = *(const bf16x8*)(Qh + qidx + 32);
  const bf16x8 qfl0 = *(const bf16x8*)(Ql + qidx);
  const bf16x8 qfl1 = *(const bf16x8*)(Ql + qidx + 32);

  f32x4 accO[4];
#pragma unroll
  for (int u = 0; u < 4; ++u) accO[u] = (f32x4){0.f, 0.f, 0.f, 0.f};
  float lsum = 0.f;
  const size_t qrowOff = (size_t)(b * 4096 + qbase + lq) * 4096;
  short* pw = &Plds[wave][0][0];
  const short* vbase = Vt + (size_t)b * 64 * 4096;

  for (int it = 0; it < 8; ++it) {
    const int kb = sp * 512 + it * 64;
    // K A-fragments (L2-hot; issue first so bias loads queue behind them)
    bf16x8 kh0[4], kh1[4], kl0[4], kl1[4];
#pragma unroll
    for (int t = 0; t < 4; ++t) {
      const int kidx = (b * 4096 + kb + t * 16 + lq) * 64 + quad * 8;
      kh0[t] = *(const bf16x8*)(Kh + kidx);
      kh1[t] = *(const bf16x8*)(Kh + kidx + 32);
      kl0[t] = *(const bf16x8*)(Kl + kidx);
      kl1[t] = *(const bf16x8*)(Kl + kidx + 32);
    }
    // bias loads: float4 over the 4 regs (consecutive keys), NT to spare L2.
    // In flight across the 24 QK MFMAs below.
    f32x4 bsh[4], bsw[4];
#pragma unroll
    for (int t = 0; t < 4; ++t) {
      const size_t bi = qrowOff + kb + 16 * t + 4 * quad;
      bsh[t] = __builtin_nontemporal_load((const f32x4*)(Sh + bi));
      bsw[t] = __builtin_nontemporal_load((const f32x4*)(Sw + bi));
    }
    // QK^T transposed (hi/lo 3-term): accS[t][r] = score[key=kb+16t+4quad+r][q=lq]
    f32x4 accS[4];
#pragma unroll
    for (int t = 0; t < 4; ++t) accS[t] = (f32x4){0.f, 0.f, 0.f, 0.f};
#pragma unroll
    for (int t = 0; t < 4; ++t) {
      accS[t] = mfma16(kh0[t], qfh0, accS[t]);
      accS[t] = mfma16(kh1[t], qfh1, accS[t]);
      accS[t] = mfma16(kh0[t], qfl0, accS[t]);
      accS[t] = mfma16(kh1[t], qfl1, accS[t]);
      accS[t] = mfma16(kl0[t], qfh0, accS[t]);
      accS[t] = mfma16(kl1[t], qfh1, accS[t]);
    }
    // p = exp2(qk + (sh+sw)*Cs); pack 4 consecutive keys -> one ds_write_b64
#pragma unroll
    for (int t = 0; t < 4; ++t) {
      bf16x4 pk;
#pragma unroll
      for (int r = 0; r < 4; ++r) {
        float s = fmaf(bsh[t][r] + bsw[t][r], Cs, accS[t][r]);
        float p = EXP2F(s);
        lsum += p;
        pk[r] = f2b(p);
      }
      *(bf16x4*)(pw + lq * 72 + 16 * t + 4 * quad) = pk;
    }
    // PV: A = P[q][key] via ds_read_b128, B = Vt rows (contiguous bf16x8)
#pragma unroll
    for (int c = 0; c < 2; ++c) {
      const bf16x8 pa = *(const bf16x8*)(pw + lq * 72 + c * 32 + quad * 8);
#pragma unroll
      for (int u = 0; u < 4; ++u) {
        const bf16x8 vf = *(const bf16x8*)(vbase + (size_t)(u * 16 + lq) * 4096 + kb + c * 32 + quad * 8);
        accO[u] = mfma16(pa, vf, accO[u]);
      }
    }
  }
  // lsum is per-q (q=lq) partial over this lane's keys; reduce across quads
  lsum += __shfl_xor(lsum, 16, 64);
  lsum += __shfl_xor(lsum, 32, 64);

  const int orowW = sp * 8192 + b * 4096 + qbase;
  if (quad == 0) lpart[orowW + lq] = lsum;
  // accO: O[q=4*quad+r][dv=u*16+lq]
#pragma unroll
  for (int u = 0; u < 4; ++u)
#pragma unroll
    for (int r = 0; r < 4; ++r)
      Opart[(size_t)(orowW + 4 * quad + r) * 64 + u * 16 + lq] = accO[u][r];
}

// ---------------- kernel 4: combine splits (float4 + fast rcp) ----------------
__global__ void combine_kernel(const float* __restrict__ Opart, const float* __restrict__ lpart,
                               float* __restrict__ out) {
  const int g = blockIdx.x * 256 + threadIdx.x;  // 0..131071 (x4 floats)
  const int row = g >> 4;
  f32x4 o = (f32x4){0.f, 0.f, 0.f, 0.f};
  float l = 0.f;
#pragma unroll
  for (int s = 0; s < 8; ++s) {
    o += __builtin_nontemporal_load((const f32x4*)(Opart + (size_t)s * 524288 + g * 4));
    l += lpart[s * 8192 + row];
  }
  const float rl = RCPF(l);
  *(f32x4*)(out + g * 4) = o * rl;
}

extern "C" void kernel_launch(void* const* d_in, const int* in_sizes, int n_in,
                              void* d_out, int out_size, void* d_ws, size_t ws_size,
                              hipStream_t stream) {
  const float* feature = (const float*)d_in[0];
  const float* Sh = (const float*)d_in[1];
  const float* Sw = (const float*)d_in[2];
  const float* wq = (const float*)d_in[3];
  const float* bq = (const float*)d_in[4];
  const float* wk = (const float*)d_in[5];
  const float* bk = (const float*)d_in[6];
  const float* wv = (const float*)d_in[7];
  const float* bv = (const float*)d_in[8];

  char* ws = (char*)d_ws;
  const size_t MB = 1u << 20;
  short* Qh = (short*)(ws + 0 * MB);            // 1 MB   (8192*64 bf16)
  short* Ql = (short*)(ws + 1 * MB);            // 1 MB
  short* Kh = (short*)(ws + 2 * MB);            // 1 MB
  short* Kl = (short*)(ws + 3 * MB);            // 1 MB
  short* Vt = (short*)(ws + 4 * MB);            // 1 MB   [b][64][4096]
  short* wh = (short*)(ws + 5 * MB);            // 192 KB
  short* wl = (short*)(ws + 5 * MB + 262144);   // 192 KB
  float* lpart = (float*)(ws + 5 * MB + 524288);// 256 KB [8][8192]
  float* Opart = (float*)(ws + 6 * MB);         // 16.78 MB [8][8192][64]

  wcvt_kernel<<<96, 256, 0, stream>>>(wq, wk, wv, wh, wl);
  proj_kernel<<<384, 256, 0, stream>>>(feature, wh, wl, bq, bk, bv, Qh, Ql, Kh, Kl, Vt);
  attn_kernel<<<1024, 256, 0, stream>>>(Sh, Sw, Qh, Ql, Kh, Kl, Vt, Opart, lpart);
  combine_kernel<<<512, 256, 0, stream>>>(Opart, lpart, (float*)d_out);
}

// Round 3
// 375.273 us; speedup vs baseline: 1.0952x; 1.0620x over previous
//
#include <hip/hip_runtime.h>
#include <hip/hip_bf16.h>

// RelativeAttention: out = softmax((QK^T + Sh + Sw)/8) V,  Q/K/V = feature @ W^T + b
// B=2, N=4096, D=512, DK=64.  Memory-bound on streaming Sh+Sw (268 MB -> ~43 us floor).
// R3: wave-private contiguous bias staging -> LDS (kills DRAM stream thrash + takes
// bias out of the vmcnt stream).  K hi-only in attn (Q stays hi/lo).

typedef short bf16x8 __attribute__((ext_vector_type(8)));
typedef short bf16x4 __attribute__((ext_vector_type(4)));
typedef float f32x4  __attribute__((ext_vector_type(4)));

#if __has_builtin(__builtin_amdgcn_exp2f)
#define EXP2F(x) __builtin_amdgcn_exp2f(x)
#else
#define EXP2F(x) exp2f(x)
#endif
#if __has_builtin(__builtin_amdgcn_rcpf)
#define RCPF(x) __builtin_amdgcn_rcpf(x)
#else
#define RCPF(x) (1.0f / (x))
#endif

__device__ __forceinline__ f32x4 mfma16(bf16x8 a, bf16x8 b, f32x4 c) {
  return __builtin_amdgcn_mfma_f32_16x16x32_bf16(a, b, c, 0, 0, 0);
}
__device__ __forceinline__ short f2b(float x) {
  __hip_bfloat16 h = __float2bfloat16(x);
  return __builtin_bit_cast(short, h);
}
__device__ __forceinline__ float b2f(short s) {
  return __bfloat162float(__builtin_bit_cast(__hip_bfloat16, s));
}
__device__ __forceinline__ void split_hl(float x, short& h, short& l) {
  __hip_bfloat16 bh = __float2bfloat16(x);
  h = __builtin_bit_cast(short, bh);
  l = f2b(x - __bfloat162float(bh));
}

// ---------------- kernel 1: weight fp32 -> bf16 hi/lo ----------------
__global__ void wcvt_kernel(const float* __restrict__ wq, const float* __restrict__ wk,
                            const float* __restrict__ wv,
                            short* __restrict__ wh, short* __restrict__ wl) {
  int idx = (blockIdx.x * 256 + threadIdx.x) * 4;
  int p = idx >> 15;
  int off = idx & 32767;
  const float* src = (p == 0) ? wq : (p == 1) ? wk : wv;
  f32x4 v = *(const f32x4*)(src + off);
  bf16x4 h, l;
#pragma unroll
  for (int j = 0; j < 4; ++j) { short hh, ll; split_hl(v[j], hh, ll); h[j] = hh; l[j] = ll; }
  *(bf16x4*)(wh + p * 32768 + off) = h;
  *(bf16x4*)(wl + p * 32768 + off) = l;
}

// ---------------- kernel 2: projections, p-split across waves ----------------
// Q is pre-scaled by log2(e)/8 so attn does exp2(qk + bias*Cs) directly.
__global__ __launch_bounds__(256) void proj_kernel(
    const float* __restrict__ feat, const short* __restrict__ wh, const short* __restrict__ wl,
    const float* __restrict__ bq, const float* __restrict__ bk, const float* __restrict__ bv,
    short* __restrict__ Qh, short* __restrict__ Ql,
    short* __restrict__ Kh, short* __restrict__ Kl, short* __restrict__ Vt) {
  const int lane = threadIdx.x & 63, wave = threadIdx.x >> 6;
  const int lq = lane & 15, quad = lane >> 4;
  const int wid = blockIdx.x * 4 + wave;   // 0..1535
  const int p = wid >> 9, rg = wid & 511;
  const int rbase = rg * 16;
  const float Cs = 0.18033688011112042f;   // log2(e)/8

  f32x4 acc[4];
#pragma unroll
  for (int t = 0; t < 4; ++t) acc[t] = (f32x4){0.f, 0.f, 0.f, 0.f};

  const float* frow = feat + (size_t)(rbase + lq) * 512 + quad * 8;
  const int wrow = p * 64;
  for (int ks = 0; ks < 16; ++ks) {
    f32x4 f0 = *(const f32x4*)(frow + ks * 32);
    f32x4 f1 = *(const f32x4*)(frow + ks * 32 + 4);
    bf16x8 fh, fl;
#pragma unroll
    for (int j = 0; j < 4; ++j) {
      short hh, ll;
      split_hl(f0[j], hh, ll); fh[j] = hh; fl[j] = ll;
      split_hl(f1[j], hh, ll); fh[j + 4] = hh; fl[j + 4] = ll;
    }
#pragma unroll
    for (int t = 0; t < 4; ++t) {
      const int wo = (wrow + t * 16 + lq) * 512 + ks * 32 + quad * 8;
      bf16x8 wfh = *(const bf16x8*)(wh + wo);
      bf16x8 wfl = *(const bf16x8*)(wl + wo);
      acc[t] = mfma16(fh, wfh, acc[t]);
      acc[t] = mfma16(fl, wfh, acc[t]);
      acc[t] = mfma16(fh, wfl, acc[t]);
    }
  }
  const int b = rbase >> 12, rloc = rbase & 4095;
  if (p == 0) {
#pragma unroll
    for (int t = 0; t < 4; ++t) {
      const int dk = t * 16 + lq;
      const float bb = bq[dk];
#pragma unroll
      for (int r = 0; r < 4; ++r) {
        const int row = rbase + 4 * quad + r;
        short h, l;
        split_hl((acc[t][r] + bb) * Cs, h, l);
        Qh[row * 64 + dk] = h; Ql[row * 64 + dk] = l;
      }
    }
  } else if (p == 1) {
#pragma unroll
    for (int t = 0; t < 4; ++t) {
      const int dk = t * 16 + lq;
      const float bb = bk[dk];
#pragma unroll
      for (int r = 0; r < 4; ++r) {
        const int row = rbase + 4 * quad + r;
        short h, l;
        split_hl(acc[t][r] + bb, h, l);
        Kh[row * 64 + dk] = h; Kl[row * 64 + dk] = l;
      }
    }
  } else {
#pragma unroll
    for (int t = 0; t < 4; ++t) {
      const int dk = t * 16 + lq;
      const float bb = bv[dk];
      bf16x4 vpack;
#pragma unroll
      for (int r = 0; r < 4; ++r) vpack[r] = f2b(acc[t][r] + bb);
      *(bf16x4*)(Vt + (size_t)(b * 64 + dk) * 4096 + rloc + 4 * quad) = vpack;
    }
  }
}

// ---------------- kernel 3: fused biased attention, split-K ----------------
// grid = B(2) * qtiles(64) * splits(8) = 1024 blocks, 256 threads (4 waves).
// Phase 1 (per wave): stream the wave's [16q x 512key] bias strip CONTIGUOUSLY
//   (1KB/instr, 4-deep pipeline), sum Sh+Sw, scale by Cs, park bf16 in LDS.
// Phase 2: 8 iters x 64 keys: QK (K hi x Q hi/lo), bias from LDS, exp2, PV.
// Only K/V (L2-hot) remain in the vmcnt stream -> no HBM-latency serialization.
__global__ __launch_bounds__(256, 4) void attn_kernel(
    const float* __restrict__ Sh, const float* __restrict__ Sw,
    const short* __restrict__ Qh, const short* __restrict__ Ql,
    const short* __restrict__ Kh, const short* __restrict__ Vt,
    float* __restrict__ Opart, float* __restrict__ lpart) {
  __shared__ short Plds[4][16][72];     // per-wave P[q16][key64] bf16
  __shared__ short BiasLds[4][16][520]; // per-wave (Sh+Sw)*Cs [q16][key512] bf16, pad 8
  const int bid = blockIdx.x;
  const int sp = bid & 7, qt = (bid >> 3) & 63, b = bid >> 9;
  const int tid = threadIdx.x;
  const int wave = tid >> 6, lane = tid & 63, lq = lane & 15, quad = lane >> 4;
  const int qbase = qt * 64 + wave * 16;
  const float Cs = 0.18033688011112042f;  // log2(e)/8 (Q already pre-scaled)

  // Q B-fragments first (oldest in vmcnt stream; L2-hot)
  const int qidx = (b * 4096 + qbase + lq) * 64 + quad * 8;
  const bf16x8 qfh0 = *(const bf16x8*)(Qh + qidx);
  const bf16x8 qfh1 = *(const bf16x8*)(Qh + qidx + 32);
  const bf16x8 qfl0 = *(const bf16x8*)(Ql + qidx);
  const bf16x8 qfl1 = *(const bf16x8*)(Ql + qidx + 32);

  // ---- phase 1: stage bias strip, contiguous streams, 4-deep pipeline ----
  short* bw = &BiasLds[wave][0][0];
  const float* shp = Sh + (size_t)(b * 4096 + qbase) * 4096 + sp * 512;
  const float* swp = Sw + (size_t)(b * 4096 + qbase) * 4096 + sp * 512;
  f32x4 sa[4], sc[4];
#pragma unroll
  for (int i = 0; i < 4; ++i) {
    const size_t off = (size_t)(i >> 1) * 4096 + (i & 1) * 256 + lane * 4;
    sa[i] = __builtin_nontemporal_load((const f32x4*)(shp + off));
    sc[i] = __builtin_nontemporal_load((const f32x4*)(swp + off));
  }
#pragma unroll 4
  for (int i = 0; i < 32; ++i) {
    const int sl = i & 3;
    f32x4 s = (sa[sl] + sc[sl]) * Cs;
    bf16x4 pk;
#pragma unroll
    for (int j = 0; j < 4; ++j) pk[j] = f2b(s[j]);
    *(bf16x4*)(bw + (i >> 1) * 520 + (i & 1) * 256 + lane * 4) = pk;
    if (i + 4 < 32) {
      const int in = i + 4;
      const size_t off = (size_t)(in >> 1) * 4096 + (in & 1) * 256 + lane * 4;
      sa[sl] = __builtin_nontemporal_load((const f32x4*)(shp + off));
      sc[sl] = __builtin_nontemporal_load((const f32x4*)(swp + off));
    }
  }

  // ---- phase 2: compute ----
  f32x4 accO[4];
#pragma unroll
  for (int u = 0; u < 4; ++u) accO[u] = (f32x4){0.f, 0.f, 0.f, 0.f};
  float lsum = 0.f;
  short* pw = &Plds[wave][0][0];
  const short* vbase = Vt + (size_t)b * 64 * 4096;

  for (int it = 0; it < 8; ++it) {
    const int kb = sp * 512 + it * 64;
    bf16x8 kh0[4], kh1[4];
#pragma unroll
    for (int t = 0; t < 4; ++t) {
      const int kidx = (b * 4096 + kb + t * 16 + lq) * 64 + quad * 8;
      kh0[t] = *(const bf16x8*)(Kh + kidx);
      kh1[t] = *(const bf16x8*)(Kh + kidx + 32);
    }
    // QK^T transposed: accS[t][r] = score[key=16t+4quad+r][q=lq]  (pre-scaled domain)
    f32x4 accS[4];
#pragma unroll
    for (int t = 0; t < 4; ++t) accS[t] = (f32x4){0.f, 0.f, 0.f, 0.f};
#pragma unroll
    for (int t = 0; t < 4; ++t) {
      accS[t] = mfma16(kh0[t], qfh0, accS[t]);
      accS[t] = mfma16(kh1[t], qfh1, accS[t]);
      accS[t] = mfma16(kh0[t], qfl0, accS[t]);
      accS[t] = mfma16(kh1[t], qfl1, accS[t]);
    }
    // bias from LDS, exp2, P write (all wave-private, no barriers)
#pragma unroll
    for (int t = 0; t < 4; ++t) {
      const bf16x4 bb = *(const bf16x4*)(bw + lq * 520 + it * 64 + 16 * t + 4 * quad);
      bf16x4 pk;
#pragma unroll
      for (int r = 0; r < 4; ++r) {
        float s = accS[t][r] + b2f(bb[r]);
        float p = EXP2F(s);
        lsum += p;
        pk[r] = f2b(p);
      }
      *(bf16x4*)(pw + lq * 72 + 16 * t + 4 * quad) = pk;
    }
    // PV: A = P[q][key] via ds_read_b128, B = Vt rows (contiguous bf16x8)
#pragma unroll
    for (int c = 0; c < 2; ++c) {
      const bf16x8 pa = *(const bf16x8*)(pw + lq * 72 + c * 32 + quad * 8);
#pragma unroll
      for (int u = 0; u < 4; ++u) {
        const bf16x8 vf = *(const bf16x8*)(vbase + (size_t)(u * 16 + lq) * 4096 + kb + c * 32 + quad * 8);
        accO[u] = mfma16(pa, vf, accO[u]);
      }
    }
  }
  // lsum (q=lq) partial over this lane's keys; reduce across quads
  lsum += __shfl_xor(lsum, 16, 64);
  lsum += __shfl_xor(lsum, 32, 64);

  const int orowW = sp * 8192 + b * 4096 + qbase;
  if (quad == 0) lpart[orowW + lq] = lsum;
#pragma unroll
  for (int u = 0; u < 4; ++u)
#pragma unroll
    for (int r = 0; r < 4; ++r)
      Opart[(size_t)(orowW + 4 * quad + r) * 64 + u * 16 + lq] = accO[u][r];
}

// ---------------- kernel 4: combine splits (float4 + fast rcp) ----------------
__global__ void combine_kernel(const float* __restrict__ Opart, const float* __restrict__ lpart,
                               float* __restrict__ out) {
  const int g = blockIdx.x * 256 + threadIdx.x;  // 0..131071 (x4 floats)
  const int row = g >> 4;
  f32x4 o = (f32x4){0.f, 0.f, 0.f, 0.f};
  float l = 0.f;
#pragma unroll
  for (int s = 0; s < 8; ++s) {
    o += __builtin_nontemporal_load((const f32x4*)(Opart + (size_t)s * 524288 + g * 4));
    l += lpart[s * 8192 + row];
  }
  const float rl = RCPF(l);
  *(f32x4*)(out + g * 4) = o * rl;
}

extern "C" void kernel_launch(void* const* d_in, const int* in_sizes, int n_in,
                              void* d_out, int out_size, void* d_ws, size_t ws_size,
                              hipStream_t stream) {
  const float* feature = (const float*)d_in[0];
  const float* Sh = (const float*)d_in[1];
  const float* Sw = (const float*)d_in[2];
  const float* wq = (const float*)d_in[3];
  const float* bq = (const float*)d_in[4];
  const float* wk = (const float*)d_in[5];
  const float* bk = (const float*)d_in[6];
  const float* wv = (const float*)d_in[7];
  const float* bv = (const float*)d_in[8];

  char* ws = (char*)d_ws;
  const size_t MB = 1u << 20;
  short* Qh = (short*)(ws + 0 * MB);            // 1 MB   (8192*64 bf16)
  short* Ql = (short*)(ws + 1 * MB);            // 1 MB
  short* Kh = (short*)(ws + 2 * MB);            // 1 MB
  short* Kl = (short*)(ws + 3 * MB);            // 1 MB (written by proj, unused in attn)
  short* Vt = (short*)(ws + 4 * MB);            // 1 MB   [b][64][4096]
  short* wh = (short*)(ws + 5 * MB);            // 192 KB
  short* wl = (short*)(ws + 5 * MB + 262144);   // 192 KB
  float* lpart = (float*)(ws + 5 * MB + 524288);// 256 KB [8][8192]
  float* Opart = (float*)(ws + 6 * MB);         // 16.78 MB [8][8192][64]

  wcvt_kernel<<<96, 256, 0, stream>>>(wq, wk, wv, wh, wl);
  proj_kernel<<<384, 256, 0, stream>>>(feature, wh, wl, bq, bk, bv, Qh, Ql, Kh, Kl, Vt);
  attn_kernel<<<1024, 256, 0, stream>>>(Sh, Sw, Qh, Ql, Kh, Vt, Opart, lpart);
  combine_kernel<<<512, 256, 0, stream>>>(Opart, lpart, (float*)d_out);
}